// Round 9
// baseline (132.247 us; speedup 1.0000x reference)
//
#include <hip/hip_runtime.h>
#include <math.h>

// SP_loss: s = X X^T / T (N=8192, D=256, T=0.04, groups of 4).
// loss = mean_g softplus((neg[g] - margin[g]) / T)
//   neg[g]    = T * log sum_{i in g, j not in g} exp(s[i,j])
//               -> MX-fp8 (e4m3, K=128 scaled MFMA) symmetric GEMM over
//                  upper-tri 64x64 tiles, 1 wave/WG, TPW=4 tiles/wave,
//                  no LDS / barriers / fences / ATOMICS.
//   margin[g] = exact fp32 4x4 group Gram block (hard_pos / least_pos / alpha)
//
// R9 change: ZERO global atomics. R1-R8 invariant ~40 us stall tracked the
// contended device-scope atomicAdd funnel (2048 floats = 128 lines, ~2-4K
// serialized cross-XCD RMWs per line). Now tile (ti,tj) plain-stores its 16
// row-group sums to contrib[ti][tj][*] and 16 col-group sums to
// contrib[tj][ti][*]; every slot of contrib[128][128][16] written exactly
// once (upper+diag <- rowg, strict lower <- colg) -> no init, no RMW.
// finalize sums over q. Also: per-ks bF reload + launch_bounds(64) to kill
// the R8 scratch spills (WRITE_SIZE 16.2 MB -> expect ~1.5 MB).
//
// X quantized as fp8(x * 6.005612), 6.005612^2 = 25*log2(e): MFMA with unity
// E8M0 scales yields acc = s*log2(e) -> exp2f(acc) directly (verified R8,
// absmax 0.0).

#define NROWS 8192
#define DDIM  256
#define NGRP  2048
#define NTB   128                       // 8192 / 64 tiles per dim
#define NTILES (NTB * (NTB + 1) / 2)    // 8256
#define TPW   4                         // tiles per wave
#define NWG   (NTILES / TPW)            // 2064
#define T_CONST 0.04f
#define INV_T   25.0f
#define QSCALE  6.005612043932249f      // sqrt(25 * log2(e))
#define SCALE_ONE 0x7F7F7F7Fu           // E8M0 127 = 2^0 in every byte

typedef __attribute__((ext_vector_type(8))) int   i32x8_t;
typedef __attribute__((ext_vector_type(4))) int   i32x4_t;
typedef __attribute__((ext_vector_type(4))) float f32x4_t;

__device__ __forceinline__ i32x8_t ldfrag(const unsigned char* base, int off) {
    i32x4_t lo = *(const i32x4_t*)(base + off);
    i32x4_t hi = *(const i32x4_t*)(base + off + 16);
    return __builtin_shufflevector(lo, hi, 0, 1, 2, 3, 4, 5, 6, 7);
}

// Kernel A (fused prep): blocks 0..511 convert fp32 -> fp8 e4m3 (x*QSCALE, RNE,
// x4 per thread); blocks 512..1023 compute margin[g] (4 groups/block, 1 wave).
__global__ __launch_bounds__(256) void prep_kernel(const float* __restrict__ x,
                                                   unsigned int* __restrict__ xq,
                                                   float* __restrict__ margin) {
    const int b = blockIdx.x;
    if (b < 512) {
#pragma unroll
        for (int it = 0; it < 4; ++it) {
            int gid = it * 131072 + b * 256 + threadIdx.x;
            float4 v = *(const float4*)(x + (size_t)gid * 4);
            int pk = __builtin_amdgcn_cvt_pk_fp8_f32(v.x * QSCALE, v.y * QSCALE, 0, false);
            pk = __builtin_amdgcn_cvt_pk_fp8_f32(v.z * QSCALE, v.w * QSCALE, pk, true);
            xq[gid] = (unsigned int)pk;
        }
        return;
    }
    const int g = (b - 512) * 4 + (threadIdx.x >> 6);
    const int lane = threadIdx.x & 63;
    const float* xr = x + (size_t)g * 4 * DDIM;
    float a[16];
#pragma unroll
    for (int k = 0; k < 16; ++k) a[k] = 0.f;
    for (int e = lane; e < DDIM; e += 64) {
        float vv[4];
        vv[0] = xr[e];
        vv[1] = xr[DDIM + e];
        vv[2] = xr[2 * DDIM + e];
        vv[3] = xr[3 * DDIM + e];
#pragma unroll
        for (int i = 0; i < 4; ++i)
#pragma unroll
            for (int j = 0; j < 4; ++j)
                a[i * 4 + j] = fmaf(vv[i], vv[j], a[i * 4 + j]);
    }
#pragma unroll
    for (int k = 0; k < 16; ++k) {
        float t = a[k];
        t += __shfl_xor(t, 32, 64);
        t += __shfl_xor(t, 16, 64);
        t += __shfl_xor(t, 8, 64);
        t += __shfl_xor(t, 4, 64);
        t += __shfl_xor(t, 2, 64);
        t += __shfl_xor(t, 1, 64);
        a[k] = t;
    }
    if (lane == 0) {
        float pos[16];
#pragma unroll
        for (int k = 0; k < 16; ++k) pos[k] = a[k] * INV_T;

        float mx = -pos[0];
#pragma unroll
        for (int k = 1; k < 16; ++k) mx = fmaxf(mx, -pos[k]);
        float se = 0.f;
#pragma unroll
        for (int k = 0; k < 16; ++k) se += __expf(-pos[k] - mx);
        float hard_pos = -T_CONST * (mx + __logf(se));

        float lse_row[4];
#pragma unroll
        for (int i = 0; i < 4; ++i) {
            float m2 = -pos[i * 4];
#pragma unroll
            for (int j = 1; j < 4; ++j) m2 = fmaxf(m2, -pos[i * 4 + j]);
            float s2 = 0.f;
#pragma unroll
            for (int j = 0; j < 4; ++j) s2 += __expf(-pos[i * 4 + j] - m2);
            lse_row[i] = m2 + __logf(s2);
        }
        float m3 = -lse_row[0];
#pragma unroll
        for (int i = 1; i < 4; ++i) m3 = fmaxf(m3, -lse_row[i]);
        float s3 = 0.f;
#pragma unroll
        for (int i = 0; i < 4; ++i) s3 += __expf(-lse_row[i] - m3);
        float least_pos = T_CONST * (m3 + __logf(s3));

        float alpha = (hard_pos >= 0.f)
                          ? (2.f * least_pos * hard_pos) / (hard_pos + least_pos)
                          : 0.f;
        margin[g] = alpha * hard_pos + (1.f - alpha) * least_pos;
    }
}

// Kernel B: one wave per WG, TPW=4 consecutive upper-tri 64x64 tiles.
// acc C/D layout (verified R4-R8): col = ni*16 + l16, row = mi*16 + quad*4 + reg
// -> reg spans exactly one group of 4 rows. Results go to contrib[][][] via
// plain stores (each slot written exactly once across the whole grid).
__global__ __launch_bounds__(64) void gemm_exp_contrib(const unsigned char* __restrict__ xq,
                                                       float* __restrict__ contrib) {
    // decode first tile (ti, tj), ti <= tj: off(ti) = ti*(257-ti)/2
    const int idx0 = blockIdx.x * TPW;
    int ti = (int)((257.0f - sqrtf(66049.0f - 8.0f * (float)idx0)) * 0.5f);
    while (ti * (257 - ti) / 2 > idx0) --ti;
    while ((ti + 1) * (256 - ti) / 2 <= idx0) ++ti;
    int tj = ti + (idx0 - ti * (257 - ti) / 2);

    const int lane = threadIdx.x;
    const int quad = lane >> 4;
    const int l16 = lane & 15;

    // per-lane fragment byte offsets: voff[ks*4+i] = ((i*16+l16)<<8) + ks*128 + quad*32
    int voff[8];
#pragma unroll
    for (int z = 0; z < 8; ++z)
        voff[z] = (((z & 3) * 16 + l16) << 8) + (z >> 2) * 128 + quad * 32;

    i32x8_t aF[2][4];   // A fragments, full K, persist across tiles (64 VGPRs)
    int curTi = -1;

    for (int t = 0; t < TPW; ++t) {
        const bool diag = (ti == tj);

        if (ti != curTi) {   // wave-uniform; true ~once per wave
            curTi = ti;
            const unsigned char* ab = xq + ((size_t)ti << 14);
#pragma unroll
            for (int z = 0; z < 8; ++z) aF[z >> 2][z & 3] = ldfrag(ab, voff[z]);
        }

        f32x4_t acc[4][4];
#pragma unroll
        for (int i = 0; i < 4; ++i)
#pragma unroll
            for (int j = 0; j < 4; ++j)
                acc[i][j] = (f32x4_t){0.f, 0.f, 0.f, 0.f};

        const unsigned char* bb = xq + ((size_t)tj << 14);
#pragma unroll
        for (int ks = 0; ks < 2; ++ks) {
            i32x8_t bF[4];
#pragma unroll
            for (int ni = 0; ni < 4; ++ni) bF[ni] = ldfrag(bb, voff[ks * 4 + ni]);
#pragma unroll
            for (int mi = 0; mi < 4; ++mi)
#pragma unroll
                for (int ni = 0; ni < 4; ++ni)
                    acc[mi][ni] = __builtin_amdgcn_mfma_scale_f32_16x16x128_f8f6f4(
                        aF[ks][mi], bF[ni], acc[mi][ni],
                        0, 0,                       // fp8 e4m3 A and B
                        0, (int)SCALE_ONE,          // scale A = 1
                        0, (int)SCALE_ONE);         // scale B = 1
        }

        // ---- epilogue: acc = s*log2(e); exp2 + group partials ----
        float rowg[4] = {0.f, 0.f, 0.f, 0.f};
        float colp[4] = {0.f, 0.f, 0.f, 0.f};

        if (!diag) {
#pragma unroll
            for (int mi = 0; mi < 4; ++mi)
#pragma unroll
                for (int ni = 0; ni < 4; ++ni) {
                    float s4 = exp2f(acc[mi][ni][0]) + exp2f(acc[mi][ni][1])
                             + exp2f(acc[mi][ni][2]) + exp2f(acc[mi][ni][3]);
                    rowg[mi] += s4;
                    colp[ni] += s4;
                }
        } else {
#pragma unroll
            for (int mi = 0; mi < 4; ++mi) {
                const int rgrp = mi * 4 + quad;
#pragma unroll
                for (int ni = 0; ni < 4; ++ni) {
                    const int cgrp = ni * 4 + (l16 >> 2);
                    if (cgrp != rgrp) {
                        float s4 = exp2f(acc[mi][ni][0]) + exp2f(acc[mi][ni][1])
                                 + exp2f(acc[mi][ni][2]) + exp2f(acc[mi][ni][3]);
                        rowg[mi] += s4;   // rows only on diag
                    }
                }
            }
        }

        // row groups -> contrib[ti][tj][mi*4+quad] (plain store, written once)
        float* crow = contrib + (((size_t)ti * NTB + tj) << 4);
#pragma unroll
        for (int mi = 0; mi < 4; ++mi) {
            float v = rowg[mi];
            v += __shfl_xor(v, 1, 64);
            v += __shfl_xor(v, 2, 64);
            v += __shfl_xor(v, 4, 64);
            v += __shfl_xor(v, 8, 64);
            if (l16 == 0) crow[mi * 4 + quad] = v;
        }
        if (!diag) {
            // col groups -> contrib[tj][ti][ni*4+(l16>>2)]
            float* ccol = contrib + (((size_t)tj * NTB + ti) << 4);
#pragma unroll
            for (int ni = 0; ni < 4; ++ni) {
                float v = colp[ni];
                v += __shfl_xor(v, 16, 64);
                v += __shfl_xor(v, 32, 64);
                v += __shfl_xor(v, 1, 64);
                v += __shfl_xor(v, 2, 64);
                if (quad == 0 && (l16 & 3) == 0) ccol[ni * 4 + (l16 >> 2)] = v;
            }
        }

        // advance to next upper-tri tile
        ++tj;
        if (tj == NTB) { ++ti; tj = ti; }
    }
}

// Kernel C: neg[g] = T*log(sum_q contrib[g>>4][q][g&15]);
// loss = mean softplus((neg - margin)/T). Single WG.
__global__ __launch_bounds__(256) void finalize_kernel(const float* __restrict__ contrib,
                                                       const float* __restrict__ margin,
                                                       float* __restrict__ out) {
    const int tid = threadIdx.x;
    float local = 0.f;
#pragma unroll
    for (int k = 0; k < 8; ++k) {
        const int g = tid + k * 256;
        const int p = g >> 4;
        const int idx = g & 15;
        const float* base = contrib + (((size_t)p * NTB) << 4) + idx;
        float s = 0.f;
        for (int q = 0; q < NTB; ++q) s += base[q << 4];
        float z = __logf(s) - margin[g] * INV_T;   // (neg - margin)/T
        local += (z > 30.f) ? z : log1pf(__expf(z));
    }
    local += __shfl_xor(local, 1, 64);
    local += __shfl_xor(local, 2, 64);
    local += __shfl_xor(local, 4, 64);
    local += __shfl_xor(local, 8, 64);
    local += __shfl_xor(local, 16, 64);
    local += __shfl_xor(local, 32, 64);
    __shared__ float wsum[4];
    if ((tid & 63) == 0) wsum[tid >> 6] = local;
    __syncthreads();
    if (tid == 0) out[0] = (wsum[0] + wsum[1] + wsum[2] + wsum[3]) * (1.f / (float)NGRP);
}

extern "C" void kernel_launch(void* const* d_in, const int* in_sizes, int n_in,
                              void* d_out, int out_size, void* d_ws, size_t ws_size,
                              hipStream_t stream) {
    const float* x = (const float*)d_in[0];
    float* out = (float*)d_out;

    unsigned int* xq = (unsigned int*)d_ws;                                  // 2 MiB fp8 X*c
    float* contrib = (float*)((char*)d_ws + (size_t)NROWS * DDIM);           // 1 MiB partials
    float* margin = contrib + (size_t)NTB * NTB * 16;                        // 8 KiB

    prep_kernel<<<1024, 256, 0, stream>>>(x, xq, margin);
    gemm_exp_contrib<<<NWG, 64, 0, stream>>>((const unsigned char*)xq, contrib);
    finalize_kernel<<<1, 256, 0, stream>>>(contrib, margin, out);
}

// Round 10
// 111.388 us; speedup vs baseline: 1.1873x; 1.1873x over previous
//
#include <hip/hip_runtime.h>
#include <math.h>

// SP_loss: s = X X^T / T (N=8192, D=256, T=0.04, groups of 4).
// loss = mean_g softplus((neg[g] - margin[g]) / T)
//   neg[g]    = T * log sum_{i in g, j not in g} exp(s[i,j])
//               -> MX-fp8 (e4m3, K=128 scaled MFMA) symmetric GEMM over
//                  upper-tri 64x64 tiles, 1 wave/WG, TPW=4 tiles/wave,
//                  no LDS / barriers / fences / atomics in the hot kernel.
//   margin[g] = exact fp32 4x4 group Gram block (hard_pos / least_pos / alpha)
//
// R10: (1) parallel finalize (8 WGs, fixes R9's 20 us single-WG regression);
// (2) all 16 B-fragment loads batched before one vmcnt wait per tile;
// (3) row shfl-reduction deferred across each wave's ti-run (3 of 4 tiles
// skip the 4-hop ds_permute chain; their contrib slots get zero stores to
// preserve the write-once invariant).
// Cross-round evidence (R2-R9): gemm pinned at 44-57 us across 6 structural
// variants -> external clock/latency floor; this round harvests the rest.
//
// X quantized as fp8(x * 6.005612), 6.005612^2 = 25*log2(e): MFMA with unity
// E8M0 scales yields acc = s*log2(e) -> exp2f(acc) directly (verified R8/R9,
// absmax 0.0).

#define NROWS 8192
#define DDIM  256
#define NGRP  2048
#define NTB   128                       // 8192 / 64 tiles per dim
#define NTILES (NTB * (NTB + 1) / 2)    // 8256
#define TPW   4                         // tiles per wave
#define NWG   (NTILES / TPW)            // 2064
#define T_CONST 0.04f
#define INV_T   25.0f
#define QSCALE  6.005612043932249f      // sqrt(25 * log2(e))
#define SCALE_ONE 0x7F7F7F7Fu           // E8M0 127 = 2^0 in every byte

typedef __attribute__((ext_vector_type(8))) int   i32x8_t;
typedef __attribute__((ext_vector_type(4))) int   i32x4_t;
typedef __attribute__((ext_vector_type(4))) float f32x4_t;

__device__ __forceinline__ i32x8_t ldfrag(const unsigned char* base, int off) {
    i32x4_t lo = *(const i32x4_t*)(base + off);
    i32x4_t hi = *(const i32x4_t*)(base + off + 16);
    return __builtin_shufflevector(lo, hi, 0, 1, 2, 3, 4, 5, 6, 7);
}

// Kernel A (fused prep): blocks 0..511 convert fp32 -> fp8 e4m3 (x*QSCALE, RNE,
// x4 per thread) + zero out[0]; blocks 512..1023 compute margin[g]
// (4 groups/block, 1 wave each).
__global__ __launch_bounds__(256) void prep_kernel(const float* __restrict__ x,
                                                   unsigned int* __restrict__ xq,
                                                   float* __restrict__ margin,
                                                   float* __restrict__ out) {
    const int b = blockIdx.x;
    if (b < 512) {
        if (b == 0 && threadIdx.x == 0) out[0] = 0.f;   // finalize atomicAdds into it
#pragma unroll
        for (int it = 0; it < 4; ++it) {
            int gid = it * 131072 + b * 256 + threadIdx.x;
            float4 v = *(const float4*)(x + (size_t)gid * 4);
            int pk = __builtin_amdgcn_cvt_pk_fp8_f32(v.x * QSCALE, v.y * QSCALE, 0, false);
            pk = __builtin_amdgcn_cvt_pk_fp8_f32(v.z * QSCALE, v.w * QSCALE, pk, true);
            xq[gid] = (unsigned int)pk;
        }
        return;
    }
    const int g = (b - 512) * 4 + (threadIdx.x >> 6);
    const int lane = threadIdx.x & 63;
    const float* xr = x + (size_t)g * 4 * DDIM;
    float a[16];
#pragma unroll
    for (int k = 0; k < 16; ++k) a[k] = 0.f;
    for (int e = lane; e < DDIM; e += 64) {
        float vv[4];
        vv[0] = xr[e];
        vv[1] = xr[DDIM + e];
        vv[2] = xr[2 * DDIM + e];
        vv[3] = xr[3 * DDIM + e];
#pragma unroll
        for (int i = 0; i < 4; ++i)
#pragma unroll
            for (int j = 0; j < 4; ++j)
                a[i * 4 + j] = fmaf(vv[i], vv[j], a[i * 4 + j]);
    }
#pragma unroll
    for (int k = 0; k < 16; ++k) {
        float t = a[k];
        t += __shfl_xor(t, 32, 64);
        t += __shfl_xor(t, 16, 64);
        t += __shfl_xor(t, 8, 64);
        t += __shfl_xor(t, 4, 64);
        t += __shfl_xor(t, 2, 64);
        t += __shfl_xor(t, 1, 64);
        a[k] = t;
    }
    if (lane == 0) {
        float pos[16];
#pragma unroll
        for (int k = 0; k < 16; ++k) pos[k] = a[k] * INV_T;

        float mx = -pos[0];
#pragma unroll
        for (int k = 1; k < 16; ++k) mx = fmaxf(mx, -pos[k]);
        float se = 0.f;
#pragma unroll
        for (int k = 0; k < 16; ++k) se += __expf(-pos[k] - mx);
        float hard_pos = -T_CONST * (mx + __logf(se));

        float lse_row[4];
#pragma unroll
        for (int i = 0; i < 4; ++i) {
            float m2 = -pos[i * 4];
#pragma unroll
            for (int j = 1; j < 4; ++j) m2 = fmaxf(m2, -pos[i * 4 + j]);
            float s2 = 0.f;
#pragma unroll
            for (int j = 0; j < 4; ++j) s2 += __expf(-pos[i * 4 + j] - m2);
            lse_row[i] = m2 + __logf(s2);
        }
        float m3 = -lse_row[0];
#pragma unroll
        for (int i = 1; i < 4; ++i) m3 = fmaxf(m3, -lse_row[i]);
        float s3 = 0.f;
#pragma unroll
        for (int i = 0; i < 4; ++i) s3 += __expf(-lse_row[i] - m3);
        float least_pos = T_CONST * (m3 + __logf(s3));

        float alpha = (hard_pos >= 0.f)
                          ? (2.f * least_pos * hard_pos) / (hard_pos + least_pos)
                          : 0.f;
        margin[g] = alpha * hard_pos + (1.f - alpha) * least_pos;
    }
}

// Kernel B: one wave per WG, TPW=4 consecutive upper-tri 64x64 tiles.
// acc C/D layout (verified R4-R9): col = ni*16 + l16, row = mi*16 + quad*4 + reg
// -> reg spans exactly one group of 4 rows. contrib[p][q][idx] written exactly
// once across the grid: p<=q slots from (possibly run-combined) row sums or
// explicit zeros, p>q slots from col sums of tile (q,p).
__global__ __launch_bounds__(64, 1) void gemm_exp_contrib(const unsigned char* __restrict__ xq,
                                                          float* __restrict__ contrib) {
    // decode first tile (ti, tj), ti <= tj: off(ti) = ti*(257-ti)/2
    const int idx0 = blockIdx.x * TPW;
    int ti = (int)((257.0f - sqrtf(66049.0f - 8.0f * (float)idx0)) * 0.5f);
    while (ti * (257 - ti) / 2 > idx0) --ti;
    while ((ti + 1) * (256 - ti) / 2 <= idx0) ++ti;
    int tj = ti + (idx0 - ti * (257 - ti) / 2);

    const int lane = threadIdx.x;
    const int quad = lane >> 4;
    const int l16 = lane & 15;

    // per-lane fragment byte offsets: voff[ks*4+i] = ((i*16+l16)<<8) + ks*128 + quad*32
    int voff[8];
#pragma unroll
    for (int z = 0; z < 8; ++z)
        voff[z] = (((z & 3) * 16 + l16) << 8) + (z >> 2) * 128 + quad * 32;

    i32x8_t aF[2][4];            // A fragments, full K, persist across the run
    int curTi = -1;

    int runTi = ti, runTj = tj;  // first tile of the current same-ti run
    bool isStart = true;
    float rowgAcc[4] = {0.f, 0.f, 0.f, 0.f};

    for (int t = 0; t < TPW; ++t) {
        const bool diag = (ti == tj);

        if (ti != curTi) {       // wave-uniform; ~once per wave
            curTi = ti;
            const unsigned char* ab = xq + ((size_t)ti << 14);
#pragma unroll
            for (int z = 0; z < 8; ++z) aF[z >> 2][z & 3] = ldfrag(ab, voff[z]);
        }

        // batch ALL 16 B-fragment loads, single implicit vmcnt wait at first MFMA
        i32x8_t bF[2][4];
        {
            const unsigned char* bb = xq + ((size_t)tj << 14);
#pragma unroll
            for (int z = 0; z < 8; ++z) bF[z >> 2][z & 3] = ldfrag(bb, voff[z]);
        }

        f32x4_t acc[4][4];
#pragma unroll
        for (int i = 0; i < 4; ++i)
#pragma unroll
            for (int j = 0; j < 4; ++j)
                acc[i][j] = (f32x4_t){0.f, 0.f, 0.f, 0.f};

#pragma unroll
        for (int ks = 0; ks < 2; ++ks)
#pragma unroll
            for (int mi = 0; mi < 4; ++mi)
#pragma unroll
                for (int ni = 0; ni < 4; ++ni)
                    acc[mi][ni] = __builtin_amdgcn_mfma_scale_f32_16x16x128_f8f6f4(
                        aF[ks][mi], bF[ks][ni], acc[mi][ni],
                        0, 0,                       // fp8 e4m3 A and B
                        0, (int)SCALE_ONE,          // scale A = 1
                        0, (int)SCALE_ONE);         // scale B = 1

        // ---- epilogue: acc = s*log2(e); exp2 + group partials ----
        float colp[4] = {0.f, 0.f, 0.f, 0.f};
        if (!diag) {
#pragma unroll
            for (int mi = 0; mi < 4; ++mi)
#pragma unroll
                for (int ni = 0; ni < 4; ++ni) {
                    float s4 = exp2f(acc[mi][ni][0]) + exp2f(acc[mi][ni][1])
                             + exp2f(acc[mi][ni][2]) + exp2f(acc[mi][ni][3]);
                    rowgAcc[mi] += s4;
                    colp[ni] += s4;
                }
        } else {
#pragma unroll
            for (int mi = 0; mi < 4; ++mi) {
                const int rgrp = mi * 4 + quad;
#pragma unroll
                for (int ni = 0; ni < 4; ++ni) {
                    const int cgrp = ni * 4 + (l16 >> 2);
                    if (cgrp != rgrp) {
                        float s4 = exp2f(acc[mi][ni][0]) + exp2f(acc[mi][ni][1])
                                 + exp2f(acc[mi][ni][2]) + exp2f(acc[mi][ni][3]);
                        rowgAcc[mi] += s4;   // rows only on diag
                    }
                }
            }
        }

        // non-run-start tiles: their row slot gets zeros (combined sum lands
        // in the run-start slot at flush)
        if (!isStart && l16 == 0) {
            float* crow = contrib + (((size_t)ti * NTB + tj) << 4);
#pragma unroll
            for (int mi = 0; mi < 4; ++mi) crow[mi * 4 + quad] = 0.f;
        }

        if (!diag) {
            // col groups -> contrib[tj][ti][ni*4+(l16>>2)] (per tile)
            float* ccol = contrib + (((size_t)tj * NTB + ti) << 4);
#pragma unroll
            for (int ni = 0; ni < 4; ++ni) {
                float v = colp[ni];
                v += __shfl_xor(v, 16, 64);
                v += __shfl_xor(v, 32, 64);
                v += __shfl_xor(v, 1, 64);
                v += __shfl_xor(v, 2, 64);
                if (quad == 0 && (l16 & 3) == 0) ccol[ni * 4 + (l16 >> 2)] = v;
            }
        }

        // advance; flush the run's combined row sums when ti changes or wave ends
        int nti = ti, ntj = tj + 1;
        if (ntj == NTB) { ++nti; ntj = nti; }
        const bool flush = (t == TPW - 1) || (nti != runTi);
        if (flush) {
            float* crow = contrib + (((size_t)runTi * NTB + runTj) << 4);
#pragma unroll
            for (int mi = 0; mi < 4; ++mi) {
                float v = rowgAcc[mi];
                v += __shfl_xor(v, 1, 64);
                v += __shfl_xor(v, 2, 64);
                v += __shfl_xor(v, 4, 64);
                v += __shfl_xor(v, 8, 64);
                if (l16 == 0) crow[mi * 4 + quad] = v;
                rowgAcc[mi] = 0.f;
            }
            runTi = nti; runTj = ntj;
            isStart = true;
        } else {
            isStart = false;
        }
        ti = nti; tj = ntj;
    }
}

// Kernel C: 8 WGs x 256 threads, one thread per group g.
// neg[g] = T*log(sum_q contrib[g>>4][q][g&15]); block-reduced softplus sums
// atomicAdd into out[0] (zeroed by prep). 8 atomics total.
__global__ __launch_bounds__(256) void finalize_kernel(const float* __restrict__ contrib,
                                                       const float* __restrict__ margin,
                                                       float* __restrict__ out) {
    const int tid = threadIdx.x;
    const int g = blockIdx.x * 256 + tid;
    const int p = g >> 4;
    const int idx = g & 15;
    const float* base = contrib + (((size_t)p * NTB) << 4) + idx;
    float s = 0.f;
#pragma unroll 4
    for (int q = 0; q < NTB; ++q) s += base[(size_t)q << 4];
    float z = __logf(s) - margin[g] * INV_T;   // (neg - margin)/T
    float local = (z > 30.f) ? z : log1pf(__expf(z));

    local += __shfl_xor(local, 1, 64);
    local += __shfl_xor(local, 2, 64);
    local += __shfl_xor(local, 4, 64);
    local += __shfl_xor(local, 8, 64);
    local += __shfl_xor(local, 16, 64);
    local += __shfl_xor(local, 32, 64);
    __shared__ float wsum[4];
    if ((tid & 63) == 0) wsum[tid >> 6] = local;
    __syncthreads();
    if (tid == 0)
        atomicAdd(out, (wsum[0] + wsum[1] + wsum[2] + wsum[3]) * (1.f / (float)NGRP));
}

extern "C" void kernel_launch(void* const* d_in, const int* in_sizes, int n_in,
                              void* d_out, int out_size, void* d_ws, size_t ws_size,
                              hipStream_t stream) {
    const float* x = (const float*)d_in[0];
    float* out = (float*)d_out;

    unsigned int* xq = (unsigned int*)d_ws;                                  // 2 MiB fp8 X*c
    float* contrib = (float*)((char*)d_ws + (size_t)NROWS * DDIM);           // 1 MiB partials
    float* margin = contrib + (size_t)NTB * NTB * 16;                        // 8 KiB

    prep_kernel<<<1024, 256, 0, stream>>>(x, xq, margin, out);
    gemm_exp_contrib<<<NWG, 64, 0, stream>>>((const unsigned char*)xq, contrib);
    finalize_kernel<<<8, 256, 0, stream>>>(contrib, margin, out);
}